// Round 2
// baseline (250.730 us; speedup 1.0000x reference)
//
#include <hip/hip_runtime.h>
#include <hip/hip_bf16.h>

// MyMSA: B=4 S=2048 D=1024 H=16 DH=64. fp32 in/out. bf16 MFMA, fp32 accum.
//
// R9 = R6 structure with one surgical change in attn:
//  * V is NOT staged in LDS. R6's LDS pipe was the critical resource
//    (~65% busy: 16 ds_read_b128 + 4 ds_write_b128 per wave-tile vs MFMA 47%).
//    V fragments are read directly from global (L2-resident: 256KB/bh, 16
//    blocks of the same bh pinned to one XCD by bid&63) at the byte-identical
//    addresses the old stage produced, register-prefetched ONE 32-key phase
//    ahead (ping-pong vfC/vfN, explicit names, no runtime indexing).
//    LDS traffic halves: 8 ds_read + 2 ds_write per wave-tile.
//    VGPR ~115 < 128 cap of (256,4) -> compiler has slack, no R8-style
//    live-range serialization; 4 waves/SIMD TLP covers residual L2 latency.
//  * qkv_kernel: verbatim R6 (512 blocks x 256 thr, 4 token groups).
// R8 lesson: deep register double-buffer at 2 waves/SIMD + tight VGPRs ->
// compiler moved loads to uses (VGPR 120, no scratch), serializing; 135us.

typedef unsigned short u16;
typedef unsigned int   u32;
typedef float  f32x4  __attribute__((ext_vector_type(4)));
typedef __bf16 bf16x4 __attribute__((ext_vector_type(4)));
typedef __bf16 bf16x8 __attribute__((ext_vector_type(8)));

#define NB 4
#define SS 2048
#define DDIM 1024
#define NH 16
#define DH 64

static __device__ __forceinline__ float fexp2(float x) {
#if __has_builtin(__builtin_amdgcn_exp2f)
    return __builtin_amdgcn_exp2f(x);
#else
    return exp2f(x);
#endif
}
static __device__ __forceinline__ bf16x4 cvt4(f32x4 v) {
    return __builtin_convertvector(v, bf16x4);   // v_cvt_pk_bf16_f32 on gfx950
}
static __device__ __forceinline__ bf16x8 cvt8(f32x4 lo, f32x4 hi) {
    return __builtin_shufflevector(cvt4(lo), cvt4(hi), 0, 1, 2, 3, 4, 5, 6, 7);
}

// ---------------- Kernel 1: QKV projection (R6 verbatim) ----------------
// grid: 64 * 8 = 512 blocks (bh = bid&63 -> co-XCD with attn), 256 threads.
#define WST 72   // W_lds row stride (u16): 144B

__global__ __launch_bounds__(256) void qkv_kernel(
        const float* __restrict__ x,
        const float* __restrict__ Wq, const float* __restrict__ bq,
        const float* __restrict__ Wk, const float* __restrict__ bk,
        const float* __restrict__ Wv, const float* __restrict__ bv,
        u16* __restrict__ Qw, u16* __restrict__ Kw, u16* __restrict__ Vt) {
    __shared__ __align__(16) u16 W_lds[3 * DH * WST];   // 27.6 KB

    const int tid  = threadIdx.x;
    const int w    = tid >> 6;
    const int lane = tid & 63;
    const int quad = lane >> 4;
    const int c    = lane & 15;
    const int bid  = blockIdx.x;
    const int bh   = bid & 63;
    const int s0   = (bid >> 6) * 256;
    const int b    = bh >> 4, h = bh & 15;

    // stage W fp32 -> bf16 into LDS
    {
        const float* Wsrc[3] = {Wq + h*DH*DH, Wk + h*DH*DH, Wv + h*DH*DH};
        #pragma unroll
        for (int j = 0; j < 6; ++j) {
            const int m = j >> 1;
            const int chunk = ((j & 1) << 8) + tid;      // 0..511 within mat
            const float* src = Wsrc[m] + chunk * 8;
            f32x4 lo = *(const f32x4*)src;
            f32x4 hi = *(const f32x4*)(src + 4);
            const int row = chunk >> 3, c8 = chunk & 7;
            *(bf16x8*)&W_lds[(m*DH + row) * WST + c8*8] = cvt8(lo, hi);
        }
    }
    __syncthreads();

    // per-wave W fragments, read from LDS ONCE, reused over 4 token groups
    bf16x8 wf[3][4][2];
    #pragma unroll
    for (int m = 0; m < 3; ++m)
        #pragma unroll
        for (int mt = 0; mt < 4; ++mt)
            #pragma unroll
            for (int kh = 0; kh < 2; ++kh)
                wf[m][mt][kh] = *(const bf16x8*)&W_lds[(m*DH + mt*16 + c) * WST + kh*32 + quad*8];

    f32x4 biasQK[2][4];
    float biasV[4];
    #pragma unroll
    for (int mt = 0; mt < 4; ++mt) {
        biasQK[0][mt] = *(const f32x4*)(bq + h*DH + mt*16 + quad*4);
        biasQK[1][mt] = *(const f32x4*)(bk + h*DH + mt*16 + quad*4);
        biasV[mt] = bv[h*DH + mt*16 + c];
    }

    const size_t qkbase = (size_t)bh * SS * DH;
    const size_t vtbase = (size_t)bh * DH * SS;

    #pragma unroll 1
    for (int g = 0; g < 4; ++g) {
        const int sb = s0 + w*64 + g*16;      // group tokens: sb + c
        const float* xr = x + ((size_t)(b * SS + sb + c)) * DDIM + h * DH;
        bf16x8 xb[2];
        #pragma unroll
        for (int kh = 0; kh < 2; ++kh) {
            f32x4 lo = *(const f32x4*)(xr + kh*32 + quad*8);
            f32x4 hi = *(const f32x4*)(xr + kh*32 + quad*8 + 4);
            xb[kh] = cvt8(lo, hi);
        }

        const int srow = sb + c;
        const int tq = srow & 31;
        const int sK = (srow & ~31) | ((tq & 4) << 2) | ((tq >> 3) << 2) | (tq & 3);

        // Q, K: swapped operands (A = W frag, B = X^T frag)
        #pragma unroll
        for (int m = 0; m < 2; ++m) {
            const float scale = (m == 0) ? 0.18033688f : 1.0f;  // 0.125*log2(e)
            u16* base = (m == 0 ? Qw : Kw) + qkbase + (size_t)(m == 0 ? srow : sK) * DH;
            #pragma unroll
            for (int mt = 0; mt < 4; ++mt) {
                f32x4 acc = {0.f, 0.f, 0.f, 0.f};
                acc = __builtin_amdgcn_mfma_f32_16x16x32_bf16(wf[m][mt][0], xb[0], acc, 0, 0, 0);
                acc = __builtin_amdgcn_mfma_f32_16x16x32_bf16(wf[m][mt][1], xb[1], acc, 0, 0, 0);
                f32x4 v = (acc + biasQK[m][mt]) * scale;
                *(bf16x4*)(base + mt*16 + quad*4) = cvt4(v);     // b64 store
            }
        }
        // V: non-swapped (A = X frag, B = W frag) -> C rows = tokens
        #pragma unroll
        for (int nt = 0; nt < 4; ++nt) {
            f32x4 acc = {0.f, 0.f, 0.f, 0.f};
            acc = __builtin_amdgcn_mfma_f32_16x16x32_bf16(xb[0], wf[2][nt][0], acc, 0, 0, 0);
            acc = __builtin_amdgcn_mfma_f32_16x16x32_bf16(xb[1], wf[2][nt][1], acc, 0, 0, 0);
            f32x4 v = acc + biasV[nt];
            u16* dst = Vt + vtbase + (size_t)(nt*16 + c) * SS + sb + quad*4;
            *(bf16x4*)dst = cvt4(v);                             // b64 along s
        }
    }
}

// ---------------- Kernel 2: flash attention, K in LDS, V direct ----------------
// grid: 64 * 16 = 1024 blocks, 256 threads (4 waves x 32 q = 2 qt).
#define KT 64
#define KST 72   // K_lds row stride (u16)

#define ATTN_G(goff, vf)                                                       \
    do {                                                                       \
        bf16x8 kfA0 = *(const bf16x8*)&Kl[((goff) + c) * KST + quad*8];        \
        bf16x8 kfA1 = *(const bf16x8*)&Kl[((goff) + c) * KST + 32 + quad*8];   \
        bf16x8 kfB0 = *(const bf16x8*)&Kl[((goff) + 16 + c) * KST + quad*8];   \
        bf16x8 kfB1 = *(const bf16x8*)&Kl[((goff) + 16 + c) * KST + 32 + quad*8]; \
        _Pragma("unroll")                                                      \
        for (int qt = 0; qt < 2; ++qt) {                                       \
            f32x4 sA = {0.f,0.f,0.f,0.f}, sB = {0.f,0.f,0.f,0.f};              \
            sA = __builtin_amdgcn_mfma_f32_16x16x32_bf16(kfA0, qf[qt][0], sA, 0,0,0); \
            sA = __builtin_amdgcn_mfma_f32_16x16x32_bf16(kfA1, qf[qt][1], sA, 0,0,0); \
            sB = __builtin_amdgcn_mfma_f32_16x16x32_bf16(kfB0, qf[qt][0], sB, 0,0,0); \
            sB = __builtin_amdgcn_mfma_f32_16x16x32_bf16(kfB1, qf[qt][1], sB, 0,0,0); \
            f32x4 eA, eB;                                                      \
            _Pragma("unroll")                                                  \
            for (int r = 0; r < 4; ++r) { eA[r] = fexp2(sA[r]); eB[r] = fexp2(sB[r]); } \
            bf16x8 pf = cvt8(eA, eB);                                          \
            _Pragma("unroll")                                                  \
            for (int dt = 0; dt < 4; ++dt)                                     \
                o[dt][qt] = __builtin_amdgcn_mfma_f32_16x16x32_bf16(vf[dt], pf, o[dt][qt], 0,0,0); \
            lacc[qt] = __builtin_amdgcn_mfma_f32_16x16x32_bf16(ones8, pf, lacc[qt], 0,0,0); \
        }                                                                      \
    } while (0)

__global__ __launch_bounds__(256, 4) void attn_kernel(
        const u16* __restrict__ Qw, const u16* __restrict__ Kw,
        const u16* __restrict__ Vt, float* __restrict__ out) {
    __shared__ __align__(16) u16 K_lds[2][KT * KST];   // 2 x 9.2 KB

    const int tid  = threadIdx.x;
    const int w    = tid >> 6;
    const int lane = tid & 63;
    const int quad = lane >> 4;
    const int c    = lane & 15;
    const int bid  = blockIdx.x;
    const int bh   = bid & 63;           // XCD swizzle: same bh -> same XCD
    const int q0   = (bid >> 6) * 128;
    const int qw   = q0 + w * 32;        // wave's 32 q-rows (2 qt)

    const u16* Qb = Qw + (size_t)bh * SS * DH;
    const u16* Kb = Kw + (size_t)bh * SS * DH;
    // V fragment base: byte-identical addresses to the old LDS-staged read
    // (stage was a linear copy of Vt[bh][d][t0+*]).
    const u16* Vc = Vt + (size_t)bh * DH * SS + (size_t)c * SS + quad * 8;

    // Q B-frags (n=q=c, k=d=quad*8+j)
    bf16x8 qf[2][2];
    #pragma unroll
    for (int qt = 0; qt < 2; ++qt) {
        const u16* qrow = Qb + (size_t)(qw + qt*16 + c) * DH;
        qf[qt][0] = *(const bf16x8*)(qrow + quad*8);
        qf[qt][1] = *(const bf16x8*)(qrow + 32 + quad*8);
    }

    f32x4 o[4][2];      // o[dt][qt]: O^T C-frags (col=q, row=d-local)
    f32x4 lacc[2];
    #pragma unroll
    for (int qt = 0; qt < 2; ++qt) {
        lacc[qt] = (f32x4){0.f, 0.f, 0.f, 0.f};
        #pragma unroll
        for (int dt = 0; dt < 4; ++dt) o[dt][qt] = (f32x4){0.f, 0.f, 0.f, 0.f};
    }

    bf16x8 ones8;
    { union { u16 u[8]; bf16x8 v; } one;
      #pragma unroll
      for (int i = 0; i < 8; ++i) one.u[i] = 0x3F80;
      ones8 = one.v; }

    // K staging: row = tid>>2 (0..63), 32 u16 cols per thread (2x uint4)
    const int strow = tid >> 2;
    const int stcol = (tid & 3) * 16;
    const int kofs  = strow * KST + stcol;

    uint4 kr0 = *(const uint4*)(Kb + (size_t)strow * DH + stcol);
    uint4 kr1 = *(const uint4*)(Kb + (size_t)strow * DH + stcol + 8);

    // V ping-pong: vfC = current phase's V frags, vfN = next phase's.
    // Each loaded exactly one 32-key phase before use.
    bf16x8 vfC[4], vfN[4];
    #pragma unroll
    for (int dt = 0; dt < 4; ++dt)
        vfC[dt] = *(const bf16x8*)(Vc + (size_t)(dt*16) * SS);   // t=0, g=0

    #pragma unroll 1
    for (int t0 = 0; t0 < SS; t0 += KT) {
        const int bsel = (t0 >> 6) & 1;
        u16* Kl = K_lds[bsel];
        *(uint4*)&Kl[kofs]     = kr0;
        *(uint4*)&Kl[kofs + 8] = kr1;
        __syncthreads();                       // single barrier per iter
        int tn = t0 + KT; if (tn >= SS) tn = 0;    // wrap: harmless reload
        kr0 = *(const uint4*)(Kb + (size_t)(tn + strow) * DH + stcol);
        kr1 = *(const uint4*)(Kb + (size_t)(tn + strow) * DH + stcol + 8);

        // ---- phase g=0: issue V(t0+32) loads, compute keys t0..t0+31 with vfC
        #pragma unroll
        for (int dt = 0; dt < 4; ++dt)
            vfN[dt] = *(const bf16x8*)(Vc + (size_t)(dt*16) * SS + t0 + 32);
        ATTN_G(0, vfC);

        // ---- phase g=1: issue V(tn) loads, compute keys t0+32..t0+63 with vfN
        #pragma unroll
        for (int dt = 0; dt < 4; ++dt)
            vfC[dt] = *(const bf16x8*)(Vc + (size_t)(dt*16) * SS + tn);
        ATTN_G(32, vfN);
    }

    // epilogue: lane holds token = qw + qt*16 + c, d = dt*16 + quad*4 + r
    const int b = bh >> 4, h = bh & 15;
    #pragma unroll
    for (int qt = 0; qt < 2; ++qt) {
        const float inv = 1.0f / lacc[qt][0];
        const int token = qw + qt*16 + c;
        float* orow = out + ((size_t)b * SS + token) * DDIM + h * DH;
        #pragma unroll
        for (int dt = 0; dt < 4; ++dt) {
            f32x4 vv = o[dt][qt] * inv;
            *(f32x4*)(orow + dt*16 + quad*4) = vv;
        }
    }
}

extern "C" void kernel_launch(void* const* d_in, const int* in_sizes, int n_in,
                              void* d_out, int out_size, void* d_ws, size_t ws_size,
                              hipStream_t stream) {
    const float* x  = (const float*)d_in[0];
    const float* Wq = (const float*)d_in[1];
    const float* bq = (const float*)d_in[2];
    const float* Wk = (const float*)d_in[3];
    const float* bk = (const float*)d_in[4];
    const float* Wv = (const float*)d_in[5];
    const float* bv = (const float*)d_in[6];

    // ws: Qw[bh][s][d], Kw[bh][s'][d] (s permuted per 32), Vt[bh][d][s]
    u16* Qw = (u16*)d_ws;
    u16* Kw = Qw + (size_t)NB * NH * SS * DH;
    u16* Vt = Kw + (size_t)NB * NH * SS * DH;

    qkv_kernel<<<64 * (SS / 256), 256, 0, stream>>>(
        x, Wq, bq, Wk, bk, Wv, bv, Qw, Kw, Vt);
    attn_kernel<<<64 * (SS / 128), 256, 0, stream>>>(Qw, Kw, Vt, (float*)d_out);
}

// Round 3
// 182.347 us; speedup vs baseline: 1.3750x; 1.3750x over previous
//
#include <hip/hip_runtime.h>
#include <hip/hip_bf16.h>

// MyMSA: B=4 S=2048 D=1024 H=16 DH=64. fp32 in/out. bf16 MFMA, fp32 accum.
//
// R10 = R6 structure (K AND V staged in LDS, single-barrier double-buffer)
// with qt=2 -> qt=4: each wave computes 64 q-rows, block covers 256, grid
// 512 (2 blocks/CU, 8 waves/CU, lb(256,2), VGPR budget 256, need ~190).
// Rationale: R6's LDS pipe was the critical resource (~150K cy/CU vs MFMA
// 89K); K/V ds_reads + staging ds_writes per tile are qt-INDEPENDENT, so
// qt=4 halves LDS cycles per q-row -> LDS 61K cy/CU, MFMA 89K cy/CU:
// binding resource flips to MFMA/VALU (~37us floor).
// R8/R9 lesson (both failed): fragment reads direct from global are
// uncoalesced per-lane gathers (128B-4KB lane stride); the compiler also
// sinks "register prefetch" loads to uses when VGPR-tight, serializing at
// L2 latency. LDS staging (coalesced global -> LDS scatter) is the only
// layout-converting path that works. Do not retry direct-operand loads.
// qkv_kernel: verbatim R6.

typedef unsigned short u16;
typedef unsigned int   u32;
typedef float  f32x4  __attribute__((ext_vector_type(4)));
typedef __bf16 bf16x4 __attribute__((ext_vector_type(4)));
typedef __bf16 bf16x8 __attribute__((ext_vector_type(8)));

#define NB 4
#define SS 2048
#define DDIM 1024
#define NH 16
#define DH 64

static __device__ __forceinline__ float fexp2(float x) {
#if __has_builtin(__builtin_amdgcn_exp2f)
    return __builtin_amdgcn_exp2f(x);
#else
    return exp2f(x);
#endif
}
static __device__ __forceinline__ bf16x4 cvt4(f32x4 v) {
    return __builtin_convertvector(v, bf16x4);   // v_cvt_pk_bf16_f32 on gfx950
}
static __device__ __forceinline__ bf16x8 cvt8(f32x4 lo, f32x4 hi) {
    return __builtin_shufflevector(cvt4(lo), cvt4(hi), 0, 1, 2, 3, 4, 5, 6, 7);
}

// ---------------- Kernel 1: QKV projection (R6 verbatim) ----------------
// grid: 64 * 8 = 512 blocks (bh = bid&63 -> co-XCD with attn), 256 threads.
#define WST 72   // W_lds row stride (u16): 144B

__global__ __launch_bounds__(256) void qkv_kernel(
        const float* __restrict__ x,
        const float* __restrict__ Wq, const float* __restrict__ bq,
        const float* __restrict__ Wk, const float* __restrict__ bk,
        const float* __restrict__ Wv, const float* __restrict__ bv,
        u16* __restrict__ Qw, u16* __restrict__ Kw, u16* __restrict__ Vt) {
    __shared__ __align__(16) u16 W_lds[3 * DH * WST];   // 27.6 KB

    const int tid  = threadIdx.x;
    const int w    = tid >> 6;
    const int lane = tid & 63;
    const int quad = lane >> 4;
    const int c    = lane & 15;
    const int bid  = blockIdx.x;
    const int bh   = bid & 63;
    const int s0   = (bid >> 6) * 256;
    const int b    = bh >> 4, h = bh & 15;

    // stage W fp32 -> bf16 into LDS
    {
        const float* Wsrc[3] = {Wq + h*DH*DH, Wk + h*DH*DH, Wv + h*DH*DH};
        #pragma unroll
        for (int j = 0; j < 6; ++j) {
            const int m = j >> 1;
            const int chunk = ((j & 1) << 8) + tid;      // 0..511 within mat
            const float* src = Wsrc[m] + chunk * 8;
            f32x4 lo = *(const f32x4*)src;
            f32x4 hi = *(const f32x4*)(src + 4);
            const int row = chunk >> 3, c8 = chunk & 7;
            *(bf16x8*)&W_lds[(m*DH + row) * WST + c8*8] = cvt8(lo, hi);
        }
    }
    __syncthreads();

    // per-wave W fragments, read from LDS ONCE, reused over 4 token groups
    bf16x8 wf[3][4][2];
    #pragma unroll
    for (int m = 0; m < 3; ++m)
        #pragma unroll
        for (int mt = 0; mt < 4; ++mt)
            #pragma unroll
            for (int kh = 0; kh < 2; ++kh)
                wf[m][mt][kh] = *(const bf16x8*)&W_lds[(m*DH + mt*16 + c) * WST + kh*32 + quad*8];

    f32x4 biasQK[2][4];
    float biasV[4];
    #pragma unroll
    for (int mt = 0; mt < 4; ++mt) {
        biasQK[0][mt] = *(const f32x4*)(bq + h*DH + mt*16 + quad*4);
        biasQK[1][mt] = *(const f32x4*)(bk + h*DH + mt*16 + quad*4);
        biasV[mt] = bv[h*DH + mt*16 + c];
    }

    const size_t qkbase = (size_t)bh * SS * DH;
    const size_t vtbase = (size_t)bh * DH * SS;

    #pragma unroll 1
    for (int g = 0; g < 4; ++g) {
        const int sb = s0 + w*64 + g*16;      // group tokens: sb + c
        const float* xr = x + ((size_t)(b * SS + sb + c)) * DDIM + h * DH;
        bf16x8 xb[2];
        #pragma unroll
        for (int kh = 0; kh < 2; ++kh) {
            f32x4 lo = *(const f32x4*)(xr + kh*32 + quad*8);
            f32x4 hi = *(const f32x4*)(xr + kh*32 + quad*8 + 4);
            xb[kh] = cvt8(lo, hi);
        }

        const int srow = sb + c;
        const int tq = srow & 31;
        const int sK = (srow & ~31) | ((tq & 4) << 2) | ((tq >> 3) << 2) | (tq & 3);

        // Q, K: swapped operands (A = W frag, B = X^T frag)
        #pragma unroll
        for (int m = 0; m < 2; ++m) {
            const float scale = (m == 0) ? 0.18033688f : 1.0f;  // 0.125*log2(e)
            u16* base = (m == 0 ? Qw : Kw) + qkbase + (size_t)(m == 0 ? srow : sK) * DH;
            #pragma unroll
            for (int mt = 0; mt < 4; ++mt) {
                f32x4 acc = {0.f, 0.f, 0.f, 0.f};
                acc = __builtin_amdgcn_mfma_f32_16x16x32_bf16(wf[m][mt][0], xb[0], acc, 0, 0, 0);
                acc = __builtin_amdgcn_mfma_f32_16x16x32_bf16(wf[m][mt][1], xb[1], acc, 0, 0, 0);
                f32x4 v = (acc + biasQK[m][mt]) * scale;
                *(bf16x4*)(base + mt*16 + quad*4) = cvt4(v);     // b64 store
            }
        }
        // V: non-swapped (A = X frag, B = W frag) -> C rows = tokens
        #pragma unroll
        for (int nt = 0; nt < 4; ++nt) {
            f32x4 acc = {0.f, 0.f, 0.f, 0.f};
            acc = __builtin_amdgcn_mfma_f32_16x16x32_bf16(xb[0], wf[2][nt][0], acc, 0, 0, 0);
            acc = __builtin_amdgcn_mfma_f32_16x16x32_bf16(xb[1], wf[2][nt][1], acc, 0, 0, 0);
            f32x4 v = acc + biasV[nt];
            u16* dst = Vt + vtbase + (size_t)(nt*16 + c) * SS + sb + quad*4;
            *(bf16x4*)dst = cvt4(v);                             // b64 along s
        }
    }
}

// ---------------- Kernel 2: flash attention, qt=4 ----------------
// grid: 64 * 8 = 512 blocks, 256 threads (4 waves x 64 q = 4 qt).
#define KT 64
#define KST 72   // K_lds row stride (u16)
#define VST 72   // V_lds row stride (u16)

#define ATTN_G(g)                                                              \
    do {                                                                       \
        bf16x8 kfA0 = *(const bf16x8*)&Kl[((g)*32 + c) * KST + quad*8];        \
        bf16x8 kfA1 = *(const bf16x8*)&Kl[((g)*32 + c) * KST + 32 + quad*8];   \
        bf16x8 kfB0 = *(const bf16x8*)&Kl[((g)*32 + 16 + c) * KST + quad*8];   \
        bf16x8 kfB1 = *(const bf16x8*)&Kl[((g)*32 + 16 + c) * KST + 32 + quad*8]; \
        bf16x8 vf0 = *(const bf16x8*)&Vl[( 0 + c) * VST + (g)*32 + quad*8];    \
        bf16x8 vf1 = *(const bf16x8*)&Vl[(16 + c) * VST + (g)*32 + quad*8];    \
        bf16x8 vf2 = *(const bf16x8*)&Vl[(32 + c) * VST + (g)*32 + quad*8];    \
        bf16x8 vf3 = *(const bf16x8*)&Vl[(48 + c) * VST + (g)*32 + quad*8];    \
        _Pragma("unroll")                                                      \
        for (int qt = 0; qt < 4; ++qt) {                                       \
            f32x4 sA = {0.f,0.f,0.f,0.f}, sB = {0.f,0.f,0.f,0.f};              \
            sA = __builtin_amdgcn_mfma_f32_16x16x32_bf16(kfA0, qf[qt][0], sA, 0,0,0); \
            sA = __builtin_amdgcn_mfma_f32_16x16x32_bf16(kfA1, qf[qt][1], sA, 0,0,0); \
            sB = __builtin_amdgcn_mfma_f32_16x16x32_bf16(kfB0, qf[qt][0], sB, 0,0,0); \
            sB = __builtin_amdgcn_mfma_f32_16x16x32_bf16(kfB1, qf[qt][1], sB, 0,0,0); \
            f32x4 eA, eB;                                                      \
            _Pragma("unroll")                                                  \
            for (int r = 0; r < 4; ++r) { eA[r] = fexp2(sA[r]); eB[r] = fexp2(sB[r]); } \
            bf16x8 pf = cvt8(eA, eB);                                          \
            o[0][qt] = __builtin_amdgcn_mfma_f32_16x16x32_bf16(vf0, pf, o[0][qt], 0,0,0); \
            o[1][qt] = __builtin_amdgcn_mfma_f32_16x16x32_bf16(vf1, pf, o[1][qt], 0,0,0); \
            o[2][qt] = __builtin_amdgcn_mfma_f32_16x16x32_bf16(vf2, pf, o[2][qt], 0,0,0); \
            o[3][qt] = __builtin_amdgcn_mfma_f32_16x16x32_bf16(vf3, pf, o[3][qt], 0,0,0); \
            lacc[qt] = __builtin_amdgcn_mfma_f32_16x16x32_bf16(ones8, pf, lacc[qt], 0,0,0); \
        }                                                                      \
    } while (0)

__global__ __launch_bounds__(256, 2) void attn_kernel(
        const u16* __restrict__ Qw, const u16* __restrict__ Kw,
        const u16* __restrict__ Vt, float* __restrict__ out) {
    __shared__ __align__(16) u16 K_lds[2][KT * KST];   // 2 x 9.2 KB
    __shared__ __align__(16) u16 V_lds[2][DH * VST];   // 2 x 9.2 KB

    const int tid  = threadIdx.x;
    const int w    = tid >> 6;
    const int lane = tid & 63;
    const int quad = lane >> 4;
    const int c    = lane & 15;
    const int bid  = blockIdx.x;
    const int bh   = bid & 63;           // XCD swizzle: same bh -> same XCD
    const int q0   = (bid >> 6) * 256;
    const int qw   = q0 + w * 64;        // wave's 64 q-rows (4 qt)

    const u16* Qb = Qw + (size_t)bh * SS * DH;
    const u16* Kb = Kw + (size_t)bh * SS * DH;
    const u16* Vb = Vt + (size_t)bh * DH * SS;

    // Q B-frags (n=q=c, k=d=quad*8+j)
    bf16x8 qf[4][2];
    #pragma unroll
    for (int qt = 0; qt < 4; ++qt) {
        const u16* qrow = Qb + (size_t)(qw + qt*16 + c) * DH;
        qf[qt][0] = *(const bf16x8*)(qrow + quad*8);
        qf[qt][1] = *(const bf16x8*)(qrow + 32 + quad*8);
    }

    f32x4 o[4][4];      // o[dt][qt]: O^T C-frags (col=q, row=d-local)
    f32x4 lacc[4];
    #pragma unroll
    for (int qt = 0; qt < 4; ++qt) {
        lacc[qt] = (f32x4){0.f, 0.f, 0.f, 0.f};
        #pragma unroll
        for (int dt = 0; dt < 4; ++dt) o[dt][qt] = (f32x4){0.f, 0.f, 0.f, 0.f};
    }

    bf16x8 ones8;
    { union { u16 u[8]; bf16x8 v; } one;
      #pragma unroll
      for (int i = 0; i < 8; ++i) one.u[i] = 0x3F80;
      ones8 = one.v; }

    // staging: row = tid>>2 (0..63), 32 u16 cols per thread (2x uint4)
    const int strow = tid >> 2;
    const int stcol = (tid & 3) * 16;
    const int kofs  = strow * KST + stcol;
    const int vofs  = strow * VST + stcol;

    uint4 kr0 = *(const uint4*)(Kb + (size_t)strow * DH + stcol);
    uint4 kr1 = *(const uint4*)(Kb + (size_t)strow * DH + stcol + 8);
    uint4 vr0 = *(const uint4*)(Vb + (size_t)strow * SS + stcol);
    uint4 vr1 = *(const uint4*)(Vb + (size_t)strow * SS + stcol + 8);

    #pragma unroll 1
    for (int t0 = 0; t0 < SS; t0 += KT) {
        const int bsel = (t0 >> 6) & 1;
        u16* Kl = K_lds[bsel];
        u16* Vl = V_lds[bsel];
        // store tile t0 (prefetch vmcnt drains here, after a compute phase)
        *(uint4*)&Kl[kofs]     = kr0;
        *(uint4*)&Kl[kofs + 8] = kr1;
        *(uint4*)&Vl[vofs]     = vr0;
        *(uint4*)&Vl[vofs + 8] = vr1;
        __syncthreads();                       // single barrier per iter
        int tn = t0 + KT; if (tn >= SS) tn = 0;    // wrap: harmless reload
        kr0 = *(const uint4*)(Kb + (size_t)(tn + strow) * DH + stcol);
        kr1 = *(const uint4*)(Kb + (size_t)(tn + strow) * DH + stcol + 8);
        vr0 = *(const uint4*)(Vb + (size_t)strow * SS + tn + stcol);
        vr1 = *(const uint4*)(Vb + (size_t)strow * SS + tn + stcol + 8);

        ATTN_G(0);
        ATTN_G(1);
    }

    // epilogue: lane holds token = qw + qt*16 + c, d = dt*16 + quad*4 + r
    const int b = bh >> 4, h = bh & 15;
    #pragma unroll
    for (int qt = 0; qt < 4; ++qt) {
        const float inv = 1.0f / lacc[qt][0];
        const int token = qw + qt*16 + c;
        float* orow = out + ((size_t)b * SS + token) * DDIM + h * DH;
        #pragma unroll
        for (int dt = 0; dt < 4; ++dt) {
            f32x4 vv = o[dt][qt] * inv;
            *(f32x4*)(orow + dt*16 + quad*4) = vv;
        }
    }
}

extern "C" void kernel_launch(void* const* d_in, const int* in_sizes, int n_in,
                              void* d_out, int out_size, void* d_ws, size_t ws_size,
                              hipStream_t stream) {
    const float* x  = (const float*)d_in[0];
    const float* Wq = (const float*)d_in[1];
    const float* bq = (const float*)d_in[2];
    const float* Wk = (const float*)d_in[3];
    const float* bk = (const float*)d_in[4];
    const float* Wv = (const float*)d_in[5];
    const float* bv = (const float*)d_in[6];

    // ws: Qw[bh][s][d], Kw[bh][s'][d] (s permuted per 32), Vt[bh][d][s]
    u16* Qw = (u16*)d_ws;
    u16* Kw = Qw + (size_t)NB * NH * SS * DH;
    u16* Vt = Kw + (size_t)NB * NH * SS * DH;

    qkv_kernel<<<64 * (SS / 256), 256, 0, stream>>>(
        x, Wq, bq, Wk, bk, Wv, bv, Qw, Kw, Vt);
    attn_kernel<<<64 * (SS / 256), 256, 0, stream>>>(Qw, Kw, Vt, (float*)d_out);
}

// Round 4
// 179.131 us; speedup vs baseline: 1.3997x; 1.0180x over previous
//
#include <hip/hip_runtime.h>
#include <hip/hip_bf16.h>

// MyMSA: B=4 S=2048 D=1024 H=16 DH=64. fp32 in/out. bf16 MFMA, fp32 accum.
//
// R11 = R10 (qt=4, K+V in LDS, single-barrier double-buffer) with the
// per-tile dead time attacked:
//  * KT 64 -> 128: barriers 32 -> 16, each barrier's drain/skew amortized
//    over 2x compute. LDS 71.7KB/block, 2 blocks/CU (143KB < 160).
//  * Fragment-read software pipeline: group g+1's 8 ds_read_b128 issued
//    BEFORE group g's MFMA cluster (two named frag sets, fully unrolled,
//    constant indices) -> post-barrier LDS burst spread across the tile.
//  * s_setprio(1) around each MFMA+exp2 cluster (T5; phase diversity now
//    exists between staging waves and compute waves).
// Evidence basis: R6 (qt=2,4w/SIMD) and R10 (qt=4,2w/SIMD) both ~78us with
// MfmaUtil 42% / VALU 36% / LDS 42% -> dead-time-bound, not pipe-bound.
// Totals fit total = attn + qkv + ~95us fixed harness overhead; qkv ~8us
// by cycle model -> attn is the only real lever. qkv verbatim R6.
// R8/R9 lesson stands: no direct-from-global operand fragments.

typedef unsigned short u16;
typedef unsigned int   u32;
typedef float  f32x4  __attribute__((ext_vector_type(4)));
typedef __bf16 bf16x4 __attribute__((ext_vector_type(4)));
typedef __bf16 bf16x8 __attribute__((ext_vector_type(8)));

#define NB 4
#define SS 2048
#define DDIM 1024
#define NH 16
#define DH 64

static __device__ __forceinline__ float fexp2(float x) {
#if __has_builtin(__builtin_amdgcn_exp2f)
    return __builtin_amdgcn_exp2f(x);
#else
    return exp2f(x);
#endif
}
static __device__ __forceinline__ bf16x4 cvt4(f32x4 v) {
    return __builtin_convertvector(v, bf16x4);   // v_cvt_pk_bf16_f32 on gfx950
}
static __device__ __forceinline__ bf16x8 cvt8(f32x4 lo, f32x4 hi) {
    return __builtin_shufflevector(cvt4(lo), cvt4(hi), 0, 1, 2, 3, 4, 5, 6, 7);
}

// ---------------- Kernel 1: QKV projection (R6 verbatim) ----------------
// grid: 64 * 8 = 512 blocks (bh = bid&63 -> co-XCD with attn), 256 threads.
#define WST 72   // W_lds row stride (u16): 144B

__global__ __launch_bounds__(256) void qkv_kernel(
        const float* __restrict__ x,
        const float* __restrict__ Wq, const float* __restrict__ bq,
        const float* __restrict__ Wk, const float* __restrict__ bk,
        const float* __restrict__ Wv, const float* __restrict__ bv,
        u16* __restrict__ Qw, u16* __restrict__ Kw, u16* __restrict__ Vt) {
    __shared__ __align__(16) u16 W_lds[3 * DH * WST];   // 27.6 KB

    const int tid  = threadIdx.x;
    const int w    = tid >> 6;
    const int lane = tid & 63;
    const int quad = lane >> 4;
    const int c    = lane & 15;
    const int bid  = blockIdx.x;
    const int bh   = bid & 63;
    const int s0   = (bid >> 6) * 256;
    const int b    = bh >> 4, h = bh & 15;

    // stage W fp32 -> bf16 into LDS
    {
        const float* Wsrc[3] = {Wq + h*DH*DH, Wk + h*DH*DH, Wv + h*DH*DH};
        #pragma unroll
        for (int j = 0; j < 6; ++j) {
            const int m = j >> 1;
            const int chunk = ((j & 1) << 8) + tid;      // 0..511 within mat
            const float* src = Wsrc[m] + chunk * 8;
            f32x4 lo = *(const f32x4*)src;
            f32x4 hi = *(const f32x4*)(src + 4);
            const int row = chunk >> 3, c8 = chunk & 7;
            *(bf16x8*)&W_lds[(m*DH + row) * WST + c8*8] = cvt8(lo, hi);
        }
    }
    __syncthreads();

    // per-wave W fragments, read from LDS ONCE, reused over 4 token groups
    bf16x8 wf[3][4][2];
    #pragma unroll
    for (int m = 0; m < 3; ++m)
        #pragma unroll
        for (int mt = 0; mt < 4; ++mt)
            #pragma unroll
            for (int kh = 0; kh < 2; ++kh)
                wf[m][mt][kh] = *(const bf16x8*)&W_lds[(m*DH + mt*16 + c) * WST + kh*32 + quad*8];

    f32x4 biasQK[2][4];
    float biasV[4];
    #pragma unroll
    for (int mt = 0; mt < 4; ++mt) {
        biasQK[0][mt] = *(const f32x4*)(bq + h*DH + mt*16 + quad*4);
        biasQK[1][mt] = *(const f32x4*)(bk + h*DH + mt*16 + quad*4);
        biasV[mt] = bv[h*DH + mt*16 + c];
    }

    const size_t qkbase = (size_t)bh * SS * DH;
    const size_t vtbase = (size_t)bh * DH * SS;

    #pragma unroll 1
    for (int g = 0; g < 4; ++g) {
        const int sb = s0 + w*64 + g*16;      // group tokens: sb + c
        const float* xr = x + ((size_t)(b * SS + sb + c)) * DDIM + h * DH;
        bf16x8 xb[2];
        #pragma unroll
        for (int kh = 0; kh < 2; ++kh) {
            f32x4 lo = *(const f32x4*)(xr + kh*32 + quad*8);
            f32x4 hi = *(const f32x4*)(xr + kh*32 + quad*8 + 4);
            xb[kh] = cvt8(lo, hi);
        }

        const int srow = sb + c;
        const int tq = srow & 31;
        const int sK = (srow & ~31) | ((tq & 4) << 2) | ((tq >> 3) << 2) | (tq & 3);

        // Q, K: swapped operands (A = W frag, B = X^T frag)
        #pragma unroll
        for (int m = 0; m < 2; ++m) {
            const float scale = (m == 0) ? 0.18033688f : 1.0f;  // 0.125*log2(e)
            u16* base = (m == 0 ? Qw : Kw) + qkbase + (size_t)(m == 0 ? srow : sK) * DH;
            #pragma unroll
            for (int mt = 0; mt < 4; ++mt) {
                f32x4 acc = {0.f, 0.f, 0.f, 0.f};
                acc = __builtin_amdgcn_mfma_f32_16x16x32_bf16(wf[m][mt][0], xb[0], acc, 0, 0, 0);
                acc = __builtin_amdgcn_mfma_f32_16x16x32_bf16(wf[m][mt][1], xb[1], acc, 0, 0, 0);
                f32x4 v = (acc + biasQK[m][mt]) * scale;
                *(bf16x4*)(base + mt*16 + quad*4) = cvt4(v);     // b64 store
            }
        }
        // V: non-swapped (A = X frag, B = W frag) -> C rows = tokens
        #pragma unroll
        for (int nt = 0; nt < 4; ++nt) {
            f32x4 acc = {0.f, 0.f, 0.f, 0.f};
            acc = __builtin_amdgcn_mfma_f32_16x16x32_bf16(xb[0], wf[2][nt][0], acc, 0, 0, 0);
            acc = __builtin_amdgcn_mfma_f32_16x16x32_bf16(xb[1], wf[2][nt][1], acc, 0, 0, 0);
            f32x4 v = acc + biasV[nt];
            u16* dst = Vt + vtbase + (size_t)(nt*16 + c) * SS + sb + quad*4;
            *(bf16x4*)dst = cvt4(v);                             // b64 along s
        }
    }
}

// ---------------- Kernel 2: flash attention, qt=4, KT=128 ----------------
// grid: 64 * 8 = 512 blocks, 256 threads (4 waves x 64 q = 4 qt).
#define KT 128
#define KST 72    // K_lds row stride (u16): 144B
#define VST 136   // V_lds row stride (u16): 272B (128 cols + pad 8)

#define LOAD_FRAGS(kf, vf, g) do {                                             \
        kf[0] = *(const bf16x8*)&Kl[((g)*32 + c) * KST + quad*8];              \
        kf[1] = *(const bf16x8*)&Kl[((g)*32 + c) * KST + 32 + quad*8];         \
        kf[2] = *(const bf16x8*)&Kl[((g)*32 + 16 + c) * KST + quad*8];         \
        kf[3] = *(const bf16x8*)&Kl[((g)*32 + 16 + c) * KST + 32 + quad*8];    \
        vf[0] = *(const bf16x8*)&Vl[( 0 + c) * VST + (g)*32 + quad*8];         \
        vf[1] = *(const bf16x8*)&Vl[(16 + c) * VST + (g)*32 + quad*8];         \
        vf[2] = *(const bf16x8*)&Vl[(32 + c) * VST + (g)*32 + quad*8];         \
        vf[3] = *(const bf16x8*)&Vl[(48 + c) * VST + (g)*32 + quad*8];         \
    } while (0)

#define COMPUTE_G(kf, vf) do {                                                 \
        __builtin_amdgcn_s_setprio(1);                                         \
        _Pragma("unroll")                                                      \
        for (int qt = 0; qt < 4; ++qt) {                                       \
            f32x4 sA = {0.f,0.f,0.f,0.f}, sB = {0.f,0.f,0.f,0.f};              \
            sA = __builtin_amdgcn_mfma_f32_16x16x32_bf16(kf[0], qf[qt][0], sA, 0,0,0); \
            sA = __builtin_amdgcn_mfma_f32_16x16x32_bf16(kf[1], qf[qt][1], sA, 0,0,0); \
            sB = __builtin_amdgcn_mfma_f32_16x16x32_bf16(kf[2], qf[qt][0], sB, 0,0,0); \
            sB = __builtin_amdgcn_mfma_f32_16x16x32_bf16(kf[3], qf[qt][1], sB, 0,0,0); \
            f32x4 eA, eB;                                                      \
            _Pragma("unroll")                                                  \
            for (int r = 0; r < 4; ++r) { eA[r] = fexp2(sA[r]); eB[r] = fexp2(sB[r]); } \
            bf16x8 pf = cvt8(eA, eB);                                          \
            o[0][qt] = __builtin_amdgcn_mfma_f32_16x16x32_bf16(vf[0], pf, o[0][qt], 0,0,0); \
            o[1][qt] = __builtin_amdgcn_mfma_f32_16x16x32_bf16(vf[1], pf, o[1][qt], 0,0,0); \
            o[2][qt] = __builtin_amdgcn_mfma_f32_16x16x32_bf16(vf[2], pf, o[2][qt], 0,0,0); \
            o[3][qt] = __builtin_amdgcn_mfma_f32_16x16x32_bf16(vf[3], pf, o[3][qt], 0,0,0); \
            lacc[qt] = __builtin_amdgcn_mfma_f32_16x16x32_bf16(ones8, pf, lacc[qt], 0,0,0); \
        }                                                                      \
        __builtin_amdgcn_s_setprio(0);                                         \
    } while (0)

__global__ __launch_bounds__(256, 2) void attn_kernel(
        const u16* __restrict__ Qw, const u16* __restrict__ Kw,
        const u16* __restrict__ Vt, float* __restrict__ out) {
    __shared__ __align__(16) u16 K_lds[2][KT * KST];   // 2 x 18.4 KB
    __shared__ __align__(16) u16 V_lds[2][DH * VST];   // 2 x 17.4 KB

    const int tid  = threadIdx.x;
    const int w    = tid >> 6;
    const int lane = tid & 63;
    const int quad = lane >> 4;
    const int c    = lane & 15;
    const int bid  = blockIdx.x;
    const int bh   = bid & 63;           // XCD swizzle: same bh -> same XCD
    const int q0   = (bid >> 6) * 256;
    const int qw   = q0 + w * 64;        // wave's 64 q-rows (4 qt)

    const u16* Qb = Qw + (size_t)bh * SS * DH;
    const u16* Kb = Kw + (size_t)bh * SS * DH;
    const u16* Vb = Vt + (size_t)bh * DH * SS;

    // Q B-frags (n=q=c, k=d=quad*8+j)
    bf16x8 qf[4][2];
    #pragma unroll
    for (int qt = 0; qt < 4; ++qt) {
        const u16* qrow = Qb + (size_t)(qw + qt*16 + c) * DH;
        qf[qt][0] = *(const bf16x8*)(qrow + quad*8);
        qf[qt][1] = *(const bf16x8*)(qrow + 32 + quad*8);
    }

    f32x4 o[4][4];      // o[dt][qt]: O^T C-frags (col=q, row=d-local)
    f32x4 lacc[4];
    #pragma unroll
    for (int qt = 0; qt < 4; ++qt) {
        lacc[qt] = (f32x4){0.f, 0.f, 0.f, 0.f};
        #pragma unroll
        for (int dt = 0; dt < 4; ++dt) o[dt][qt] = (f32x4){0.f, 0.f, 0.f, 0.f};
    }

    bf16x8 ones8;
    { union { u16 u[8]; bf16x8 v; } one;
      #pragma unroll
      for (int i = 0; i < 8; ++i) one.u[i] = 0x3F80;
      ones8 = one.v; }

    // K staging: 128 rows, 2 threads/row, 32 u16 each (4x uint4)
    const int krow = tid >> 1;
    const int kcol = (tid & 1) * 32;
    const int kofs = krow * KST + kcol;
    // V staging: 64 rows, 4 threads/row, 32 u16 each (4x uint4)
    const int vrow = tid >> 2;
    const int vcol = (tid & 3) * 32;
    const int vofs = vrow * VST + vcol;

    uint4 kr0 = *(const uint4*)(Kb + (size_t)krow * DH + kcol);
    uint4 kr1 = *(const uint4*)(Kb + (size_t)krow * DH + kcol + 8);
    uint4 kr2 = *(const uint4*)(Kb + (size_t)krow * DH + kcol + 16);
    uint4 kr3 = *(const uint4*)(Kb + (size_t)krow * DH + kcol + 24);
    uint4 vr0 = *(const uint4*)(Vb + (size_t)vrow * SS + vcol);
    uint4 vr1 = *(const uint4*)(Vb + (size_t)vrow * SS + vcol + 8);
    uint4 vr2 = *(const uint4*)(Vb + (size_t)vrow * SS + vcol + 16);
    uint4 vr3 = *(const uint4*)(Vb + (size_t)vrow * SS + vcol + 24);

    #pragma unroll 1
    for (int t0 = 0; t0 < SS; t0 += KT) {
        const int bsel = (t0 >> 7) & 1;
        u16* Kl = K_lds[bsel];
        u16* Vl = V_lds[bsel];
        // store tile t0 (prefetch vmcnt drains here, after a compute phase)
        *(uint4*)&Kl[kofs]      = kr0;
        *(uint4*)&Kl[kofs + 8]  = kr1;
        *(uint4*)&Kl[kofs + 16] = kr2;
        *(uint4*)&Kl[kofs + 24] = kr3;
        *(uint4*)&Vl[vofs]      = vr0;
        *(uint4*)&Vl[vofs + 8]  = vr1;
        *(uint4*)&Vl[vofs + 16] = vr2;
        *(uint4*)&Vl[vofs + 24] = vr3;
        __syncthreads();                       // single barrier per iter
        int tn = t0 + KT; if (tn >= SS) tn = 0;    // wrap: harmless reload
        kr0 = *(const uint4*)(Kb + (size_t)(tn + krow) * DH + kcol);
        kr1 = *(const uint4*)(Kb + (size_t)(tn + krow) * DH + kcol + 8);
        kr2 = *(const uint4*)(Kb + (size_t)(tn + krow) * DH + kcol + 16);
        kr3 = *(const uint4*)(Kb + (size_t)(tn + krow) * DH + kcol + 24);
        vr0 = *(const uint4*)(Vb + (size_t)vrow * SS + tn + vcol);
        vr1 = *(const uint4*)(Vb + (size_t)vrow * SS + tn + vcol + 8);
        vr2 = *(const uint4*)(Vb + (size_t)vrow * SS + tn + vcol + 16);
        vr3 = *(const uint4*)(Vb + (size_t)vrow * SS + tn + vcol + 24);

        // software-pipelined groups: read g+1 frags before computing g
        bf16x8 kfA[4], vfA[4], kfB[4], vfB[4];
        LOAD_FRAGS(kfA, vfA, 0);
        LOAD_FRAGS(kfB, vfB, 1);
        COMPUTE_G(kfA, vfA);
        LOAD_FRAGS(kfA, vfA, 2);
        COMPUTE_G(kfB, vfB);
        LOAD_FRAGS(kfB, vfB, 3);
        COMPUTE_G(kfA, vfA);
        COMPUTE_G(kfB, vfB);
    }

    // epilogue: lane holds token = qw + qt*16 + c, d = dt*16 + quad*4 + r
    const int b = bh >> 4, h = bh & 15;
    #pragma unroll
    for (int qt = 0; qt < 4; ++qt) {
        const float inv = 1.0f / lacc[qt][0];
        const int token = qw + qt*16 + c;
        float* orow = out + ((size_t)b * SS + token) * DDIM + h * DH;
        #pragma unroll
        for (int dt = 0; dt < 4; ++dt) {
            f32x4 vv = o[dt][qt] * inv;
            *(f32x4*)(orow + dt*16 + quad*4) = vv;
        }
    }
}

extern "C" void kernel_launch(void* const* d_in, const int* in_sizes, int n_in,
                              void* d_out, int out_size, void* d_ws, size_t ws_size,
                              hipStream_t stream) {
    const float* x  = (const float*)d_in[0];
    const float* Wq = (const float*)d_in[1];
    const float* bq = (const float*)d_in[2];
    const float* Wk = (const float*)d_in[3];
    const float* bk = (const float*)d_in[4];
    const float* Wv = (const float*)d_in[5];
    const float* bv = (const float*)d_in[6];

    // ws: Qw[bh][s][d], Kw[bh][s'][d] (s permuted per 32), Vt[bh][d][s]
    u16* Qw = (u16*)d_ws;
    u16* Kw = Qw + (size_t)NB * NH * SS * DH;
    u16* Vt = Kw + (size_t)NB * NH * SS * DH;

    qkv_kernel<<<64 * (SS / 256), 256, 0, stream>>>(
        x, Wq, bq, Wk, bk, Wv, bv, Qw, Kw, Vt);
    attn_kernel<<<64 * (SS / 256), 256, 0, stream>>>(Qw, Kw, Vt, (float*)d_out);
}